// Round 5
// baseline (371.977 us; speedup 1.0000x reference)
//
#include <hip/hip_runtime.h>
#include <cstdint>
#include <cstddef>

#define S_LEN 2048
#define DIM_   2048
#define NH   16
#define NKV  8
#define HD   128

typedef __attribute__((ext_vector_type(8))) __bf16 bf16x8;
typedef __attribute__((ext_vector_type(4))) float  f32x4;

typedef const __attribute__((address_space(1))) void* gptr_t;
typedef __attribute__((address_space(3))) void*       sptr_t;

static __device__ __forceinline__ float bf2f(unsigned short u) {
  union { unsigned int i; float f; } v; v.i = ((unsigned int)u) << 16; return v.f;
}
static __device__ __forceinline__ unsigned short f2bf(float f) {
  union { float f; unsigned int i; } v; v.f = f;
  unsigned int u = v.i;
  unsigned int r = (u + 0x7FFFu + ((u >> 16) & 1u)) >> 16;
  return (unsigned short)r;
}

// scale(1/sqrt(128)) * log2(e) — folded into q so softmax uses exp2 directly
#define QSCALE 0.12751744f
// defer-max threshold (T13): 8 in ln-domain -> 8*log2(e) in exp2-domain
#define RESC_THR 11.542f

// ---------------- prep: x->bf16 convert + 4 weight transpose-converts ----------------
__global__ void k_prep(const float* __restrict__ x, unsigned short* __restrict__ xb,
                       const float* __restrict__ wq, const float* __restrict__ wk,
                       const float* __restrict__ wv, const float* __restrict__ wo,
                       unsigned short* __restrict__ wqkvT, unsigned short* __restrict__ woT) {
  int bid = blockIdx.x;
  if (bid < 8192) {
    int i = bid * 256 + threadIdx.x;
    float4 v = ((const float4*)x)[i];
    ushort4 o; o.x = f2bf(v.x); o.y = f2bf(v.y); o.z = f2bf(v.z); o.w = f2bf(v.w);
    ((ushort4*)xb)[i] = o;
    return;
  }
  bid -= 8192;
  const float* src; unsigned short* dst; int N, ntx;
  if (bid < 4096)      { src = wq; dst = wqkvT;                       N = 2048; ntx = 64; }
  else if (bid < 6144) { bid -= 4096; src = wk; dst = wqkvT + (size_t)2048 * 2048; N = 1024; ntx = 32; }
  else if (bid < 8192) { bid -= 6144; src = wv; dst = wqkvT + (size_t)3072 * 2048; N = 1024; ntx = 32; }
  else                 { bid -= 8192; src = wo; dst = woT;            N = 2048; ntx = 64; }
  const int K = 2048;
  __shared__ float tile[32][33];
  int lx = threadIdx.x & 31, ly = threadIdx.x >> 5; // 32 x 8
  int r0 = (bid / ntx) * 32, c0 = (bid % ntx) * 32;
  #pragma unroll
  for (int r = 0; r < 32; r += 8)
    tile[ly + r][lx] = src[(size_t)(r0 + ly + r) * N + c0 + lx];
  __syncthreads();
  #pragma unroll
  for (int r = 0; r < 32; r += 8)
    dst[(size_t)(c0 + ly + r) * K + r0 + lx] = f2bf(tile[lx][ly + r]);
}

// ------- GEMM: C(MxN) = A(MxK) * BT(NxK)^T, bf16 in, fp32 acc, 256-col tiles -------
// ROUND-5 STRUCTURE (T3/T4/T5 from the measured catalog):
//  * BM_ x 256 tile, BK=32, 512 threads = 8 waves (2M x 4N), per-wave BM_/2 x 64
//    output = acc[BM_/32][4]. Grid = 1 block/CU (256 blocks), deep pipeline
//    replaces TLP.
//  * 4-buffer LDS ring, prefetch depth 3 K-tiles. Steady-state wait is
//    vmcnt(2*LT) -> tile kt landed while 2 newer tiles stay in flight.
//    NEVER vmcnt(0) in the main loop (T4; the m97 barrier-drain stall).
//  * ONE raw s_barrier per K-tile (no __syncthreads -> no compiler vmcnt(0)).
//    Safety: issue of tile kt+3 (overwrites the buffer read at iter kt-1)
//    sits AFTER the barrier at which all waves finished iter kt-1 reads;
//    per-wave vmcnt before the barrier makes tile kt visible to all waves.
//  * Bijective sub-tile swizzle with linear gload_lds dest (rule 21):
//    LDS L(row,ch)=(row>>1)*128B+(row&1)*64B+((ch^((row>>1)&3))*16B), applied
//    by pre-permuting the per-thread GLOBAL source; frag ds_read_b128 lands
//    2 lanes/bank = conflict-free (m136).
//  * setprio(1) around the MFMA cluster (T5).
// MODE 1: f32 C store. MODE 3: fused QKV epilogue (RoPE q/k, V transpose).
template<int MODE, int BM_>
__global__ __launch_bounds__(512, 1) void k_gemm256(
    const unsigned short* __restrict__ A, const unsigned short* __restrict__ BT,
    void* __restrict__ C, int N, int K,
    const float* __restrict__ fc, const float* __restrict__ fs,
    unsigned short* __restrict__ kb, unsigned short* __restrict__ vb) {
  constexpr int MI = BM_ / 32;          // A-frags per wave (8 or 4)
  constexpr int AR = BM_ / 128;         // A staging rounds/tile/thread (2 or 1)
  __shared__ __align__(16) unsigned short Abuf[4][BM_ * 32];
  __shared__ __align__(16) unsigned short Bbuf[4][256 * 32];
  const int t = threadIdx.x;
  const int lane = t & 63, w = t >> 6;
  const int col = lane & 15, quad = lane >> 4;
  const int wm = (w >> 2) * (BM_ / 2);
  const int wn = (w & 3) * 64;
  const int m0 = blockIdx.y * BM_, n0 = blockIdx.x * 256;
  const int NT = K >> 5;                // 32-wide K-tiles

  // per-thread staging source offsets (pre-permuted for the LDS swizzle)
  size_t srcA[2], srcB[2];
  int ldsoff[2];
  #pragma unroll
  for (int r = 0; r < 2; ++r) {
    int c = t + r * 512;
    int row = (c >> 3) * 2 + ((c >> 2) & 1);
    int ch  = (c & 3) ^ ((c >> 3) & 3);
    srcA[r] = (r < AR) ? ((size_t)(m0 + row) * K + ch * 8) : 0;
    srcB[r] = (size_t)(n0 + row) * K + ch * 8;
    ldsoff[r] = (w * 64 + r * 512) * 8;   // wave-uniform base + lane*8 (HW adds lane*16B)
  }

  f32x4 acc[MI][4];
  #pragma unroll
  for (int i = 0; i < MI; i++)
    #pragma unroll
    for (int j = 0; j < 4; j++) acc[i][j] = (f32x4){0.f, 0.f, 0.f, 0.f};

  #define ISSUE_TILE(T)                                                              \
    do {                                                                             \
      int _buf = (T) & 3;                                                            \
      _Pragma("unroll")                                                              \
      for (int r = 0; r < AR; ++r)                                                   \
        __builtin_amdgcn_global_load_lds((gptr_t)(A + srcA[r] + (size_t)(T) * 32),   \
            (sptr_t)(&Abuf[_buf][ldsoff[r]]), 16, 0, 0);                             \
      _Pragma("unroll")                                                              \
      for (int r = 0; r < 2; ++r)                                                    \
        __builtin_amdgcn_global_load_lds((gptr_t)(BT + srcB[r] + (size_t)(T) * 32),  \
            (sptr_t)(&Bbuf[_buf][ldsoff[r]]), 16, 0, 0);                             \
    } while (0)

  // prologue: 3 tiles in flight
  ISSUE_TILE(0); ISSUE_TILE(1); ISSUE_TILE(2);

  for (int kt = 0; kt < NT; ++kt) {
    // wait: tile kt landed (self), leave up to 2 tiles in flight
    if constexpr (BM_ == 256) {
      if (kt < NT - 2)       asm volatile("s_waitcnt vmcnt(8)" ::: "memory");
      else if (kt == NT - 2) asm volatile("s_waitcnt vmcnt(4)" ::: "memory");
      else                   asm volatile("s_waitcnt vmcnt(0)" ::: "memory");
    } else {
      if (kt < NT - 2)       asm volatile("s_waitcnt vmcnt(6)" ::: "memory");
      else if (kt == NT - 2) asm volatile("s_waitcnt vmcnt(3)" ::: "memory");
      else                   asm volatile("s_waitcnt vmcnt(0)" ::: "memory");
    }
    __builtin_amdgcn_s_barrier();       // all waves: tile kt visible; prev-tile reads done
    asm volatile("" ::: "memory");
    if (kt + 3 < NT) ISSUE_TILE(kt + 3);  // overwrites buffer freed by this barrier

    const int buf = kt & 3;
    bf16x8 bfr[4], afr[MI];
    #pragma unroll
    for (int ni = 0; ni < 4; ni++) {
      int row = wn + ni * 16 + col;
      bfr[ni] = *(const bf16x8*)(&Bbuf[buf][(row >> 1) * 64 + (row & 1) * 32 + ((quad ^ ((row >> 1) & 3)) * 8)]);
    }
    #pragma unroll
    for (int mi = 0; mi < MI; mi++) {
      int row = wm + mi * 16 + col;
      afr[mi] = *(const bf16x8*)(&Abuf[buf][(row >> 1) * 64 + (row & 1) * 32 + ((quad ^ ((row >> 1) & 3)) * 8)]);
    }
    __builtin_amdgcn_s_setprio(1);
    #pragma unroll
    for (int mi = 0; mi < MI; mi++)
      #pragma unroll
      for (int ni = 0; ni < 4; ni++)
        acc[mi][ni] = __builtin_amdgcn_mfma_f32_16x16x32_bf16(afr[mi], bfr[ni], acc[mi][ni], 0, 0, 0);
    __builtin_amdgcn_s_setprio(0);
  }
  #undef ISSUE_TILE

  #pragma unroll
  for (int mi = 0; mi < MI; mi++) {
    int row_base = m0 + wm + mi * 16 + quad * 4;
    #pragma unroll
    for (int ni = 0; ni < 4; ni++) {
      int col_g = n0 + wn + ni * 16 + col;
      if (MODE == 1) {
        float* O = (float*)C;
        #pragma unroll
        for (int r = 0; r < 4; r++) O[(size_t)(row_base + r) * N + col_g] = acc[mi][ni][r];
      } else {  // MODE 3
        int region = col_g >> 10;  // 0,1: q ; 2: k ; 3: v
        if (region < 3) {
          int ri = (col_g & 127) >> 1;
          float sgn = (col_g & 1) ? 1.f : -1.f;
          unsigned short* qO = (unsigned short*)C;
          #pragma unroll
          for (int r = 0; r < 4; r++) {
            int row = row_base + r;
            int s = row & (S_LEN - 1);
            float cv = fc[s * 64 + ri], sv = fs[s * 64 + ri];
            float val = acc[mi][ni][r];
            float other = __shfl_xor(val, 1);
            float res = val * cv + sgn * other * sv;
            if (region < 2) qO[(size_t)row * 2048 + col_g] = f2bf(res * QSCALE);
            else            kb[(size_t)row * 1024 + (col_g - 2048)] = f2bf(res);
          }
        } else {
          int n_local = col_g - 3072;
          int b = row_base >> 11, s = row_base & (S_LEN - 1);
          int kvh = n_local >> 7, d = n_local & (HD - 1);
          ushort4 o4;
          o4.x = f2bf(acc[mi][ni][0]); o4.y = f2bf(acc[mi][ni][1]);
          o4.z = f2bf(acc[mi][ni][2]); o4.w = f2bf(acc[mi][ni][3]);
          *(ushort4*)(&vb[((size_t)((b * NKV + kvh) * HD + d)) * S_LEN + s]) = o4;
        }
      }
    }
  }
}

// ---------------- Flash attention, causal, GQA-shared K/V ----------------
// 512-thread blocks (8 waves = 2 heads x 4 waves), ONE q-tile per block,
// grid (16,32) = 2 blocks/CU. Swapped QK^T (lane owns a q-row: 15 local fmax
// + 2 shfl), async K/V staging (T14), defer-max (T13), setprio (T5).
// ROUND-1 LESSON: __launch_bounds__ 2nd arg acts as BLOCKS/CU here; (512,6)
// capped VGPR at 40 -> accumulator spill -> 225 MB scratch traffic.
#define KLD 136   // 128 + 8 (row-to-row bank offset 4 -> conflict-free frags)
#define VLD 72    // 64 + 8
__global__ __launch_bounds__(512, 2) void k_attn(
    const unsigned short* __restrict__ q, const unsigned short* __restrict__ k,
    const unsigned short* __restrict__ vT, unsigned short* __restrict__ ao) {
  __shared__ __align__(16) unsigned short Ksm[64 * KLD];       // 17408 B
  __shared__ __align__(16) unsigned short Vsm[128 * VLD];      // 18432 B
  __shared__ __align__(16) unsigned short Psm[8 * 16 * VLD];   // 18432 B
  const int t = threadIdx.x;
  const int lane = t & 63, w = t >> 6;        // 8 waves
  const int col = lane & 15, quad = lane >> 4;
  const int g = blockIdx.x;                   // b*NKV + kvh
  const int b = g >> 3, kvh = g & 7;
  const int h = kvh * 2 + (w >> 2);           // waves 0-3: head 2g, 4-7: head 2g+1
  const int yi = blockIdx.y;                  // 0..31
  const int my_qt = (yi < 16) ? yi : 47 - yi; // balanced long/short pairing
  const int qrow = my_qt * 64 + (w & 3) * 16; // this wave's 16 query rows
  unsigned short* Pw = &Psm[w * 16 * VLD];

  // staging addresses (per thread): 2 uint4 for K, 2 uint4 for V
  const int ki0 = t >> 4,        kdc = t & 15;         // K row / d-chunk
  const int ki1 = (t + 512) >> 4;
  const int vd0 = t >> 3,        vkc = t & 7;          // V d-row / key-chunk
  const int vd1 = (t + 512) >> 3;
  const unsigned short* kgp = k + (size_t)(b * S_LEN) * (NKV * HD) + kvh * HD + kdc * 8;
  const unsigned short* vgp = vT + ((size_t)(b * NKV + kvh) * HD) * S_LEN + vkc * 8;

  bf16x8 qf[4];
  const size_t qbase = ((size_t)(b * S_LEN) + qrow + col) * DIM_ + h * HD;
  #pragma unroll
  for (int kc = 0; kc < 4; kc++) qf[kc] = *(const bf16x8*)(q + qbase + kc * 32 + quad * 8);

  f32x4 o[8];
  #pragma unroll
  for (int i = 0; i < 8; i++) o[i] = (f32x4){0.f, 0.f, 0.f, 0.f};
  float m_i = -1e30f;   // running max for q-row (qrow + col)
  float l_i = 0.f;      // running denom for q-row (qrow + col)

  const int nkt = my_qt + 1;                  // wave-uniform causal range

  // prologue: stage tile 0
  {
    uint4 kr0 = *(const uint4*)(kgp + (size_t)ki0 * (NKV * HD));
    uint4 kr1 = *(const uint4*)(kgp + (size_t)ki1 * (NKV * HD));
    uint4 vr0 = *(const uint4*)(vgp + (size_t)vd0 * S_LEN);
    uint4 vr1 = *(const uint4*)(vgp + (size_t)vd1 * S_LEN);
    *(uint4*)(&Ksm[ki0 * KLD + kdc * 8]) = kr0;
    *(uint4*)(&Ksm[ki1 * KLD + kdc * 8]) = kr1;
    *(uint4*)(&Vsm[vd0 * VLD + vkc * 8]) = vr0;
    *(uint4*)(&Vsm[vd1 * VLD + vkc * 8]) = vr1;
  }
  __syncthreads();

  for (int kt = 0; kt < nkt; ++kt) {
    const bool more = (kt + 1 < nkt);         // block-uniform
    uint4 kr0, kr1, vr0, vr1;
    if (more) {                               // issue K(t+1) early: latency hides under QK+softmax
      kr0 = *(const uint4*)(kgp + (size_t)((kt + 1) * 64 + ki0) * (NKV * HD));
      kr1 = *(const uint4*)(kgp + (size_t)((kt + 1) * 64 + ki1) * (NKV * HD));
    }

    // ---- QK^T, swapped operands: p[nt][r] = P[key = kt*64+nt*16+quad*4+r][q = col]
    float p[4][4];
    __builtin_amdgcn_s_setprio(1);
    #pragma unroll
    for (int nt = 0; nt < 4; nt++) {
      f32x4 s_acc = (f32x4){0.f, 0.f, 0.f, 0.f};
      #pragma unroll
      for (int kc = 0; kc < 4; kc++) {
        bf16x8 kf = *(const bf16x8*)(&Ksm[(nt * 16 + col) * KLD + kc * 32 + quad * 8]);
        s_acc = __builtin_amdgcn_mfma_f32_16x16x32_bf16(kf, qf[kc], s_acc, 0, 0, 0);
      }
      #pragma unroll
      for (int r = 0; r < 4; r++) p[nt][r] = s_acc[r];
    }
    __builtin_amdgcn_s_setprio(0);

    if (kt == my_qt) {  // diagonal tile: causal mask (q = qrow+col, key per reg)
      const int qglob = qrow + col;
      #pragma unroll
      for (int nt = 0; nt < 4; nt++)
        #pragma unroll
        for (int r = 0; r < 4; r++)
          if (kt * 64 + nt * 16 + quad * 4 + r > qglob) p[nt][r] = -1e30f;
    }

    // ---- softmax for this lane's q-row: 15 local fmax + 2 shfl
    float mx = fmaxf(fmaxf(fmaxf(p[0][0], p[0][1]), fmaxf(p[0][2], p[0][3])),
                     fmaxf(fmaxf(p[1][0], p[1][1]), fmaxf(p[1][2], p[1][3])));
    mx = fmaxf(mx, fmaxf(fmaxf(fmaxf(p[2][0], p[2][1]), fmaxf(p[2][2], p[2][3])),
                         fmaxf(fmaxf(p[3][0], p[3][1]), fmaxf(p[3][2], p[3][3]))));
    mx = fmaxf(mx, __shfl_xor(mx, 16));
    mx = fmaxf(mx, __shfl_xor(mx, 32));
    if (__any(mx - m_i > RESC_THR)) {   // defer-max (T13): rare
      float mn = fmaxf(m_i, mx);
      float alpha = exp2f(m_i - mn);
      m_i = mn; l_i *= alpha;
      float ar[4];
      #pragma unroll
      for (int r = 0; r < 4; r++) ar[r] = __shfl(alpha, quad * 4 + r);
      #pragma unroll
      for (int dt = 0; dt < 8; dt++)
        #pragma unroll
        for (int r = 0; r < 4; r++) o[dt][r] *= ar[r];
    }
    float rs = 0.f;
    #pragma unroll
    for (int nt = 0; nt < 4; nt++)
      #pragma unroll
      for (int r = 0; r < 4; r++) {
        float e = exp2f(p[nt][r] - m_i);
        p[nt][r] = e;
        rs += e;
      }
    rs += __shfl_xor(rs, 16);
    rs += __shfl_xor(rs, 32);
    l_i += rs;

    // ---- P -> Pw (A-layout directly: Pw[q][key]), 4x packed b64 writes
    #pragma unroll
    for (int nt = 0; nt < 4; nt++) {
      unsigned int w0 = (unsigned int)f2bf(p[nt][0]) | ((unsigned int)f2bf(p[nt][1]) << 16);
      unsigned int w1 = (unsigned int)f2bf(p[nt][2]) | ((unsigned int)f2bf(p[nt][3]) << 16);
      uint2 pk; pk.x = w0; pk.y = w1;
      *(uint2*)(&Pw[col * VLD + nt * 16 + quad * 4]) = pk;
    }

    __syncthreads();   // B1: all waves done reading Ksm (and Pw writes drained)

    if (more) {        // K(t+1) -> LDS (overlaps PV), issue V(t+1) loads
      *(uint4*)(&Ksm[ki0 * KLD + kdc * 8]) = kr0;
      *(uint4*)(&Ksm[ki1 * KLD + kdc * 8]) = kr1;
      vr0 = *(const uint4*)(vgp + (size_t)vd0 * S_LEN + (kt + 1) * 64);
      vr1 = *(const uint4*)(vgp + (size_t)vd1 * S_LEN + (kt + 1) * 64);
    }

    bf16x8 pf[2];
    #pragma unroll
    for (int kc2 = 0; kc2 < 2; kc2++)
      pf[kc2] = *(const bf16x8*)(&Pw[col * VLD + kc2 * 32 + quad * 8]);

    // ---- O += P V
    __builtin_amdgcn_s_setprio(1);
    #pragma unroll
    for (int dt = 0; dt < 8; dt++) {
      #pragma unroll
      for (int kc2 = 0; kc2 < 2; kc2++) {
        bf16x8 vf = *(const bf16x8*)(&Vsm[(dt * 16 + col) * VLD + kc2 * 32 + quad * 8]);
        o[dt] = __builtin_amdgcn_mfma_f32_16x16x32_bf16(pf[kc2], vf, o[dt], 0, 0, 0);
      }
    }
    __builtin_amdgcn_s_setprio(0);

    __syncthreads();   // B2: all waves done reading Vsm; Ksm(t+1) visible

    if (more) {        // V(t+1) -> LDS (overlaps next QK)
      *(uint4*)(&Vsm[vd0 * VLD + vkc * 8]) = vr0;
      *(uint4*)(&Vsm[vd1 * VLD + vkc * 8]) = vr1;
    }
  }

  // epilogue: 1/l for this lane's four q-rows (col -> row permute, once)
  float linv[4];
  #pragma unroll
  for (int r = 0; r < 4; r++) linv[r] = 1.f / __shfl(l_i, quad * 4 + r);
  #pragma unroll
  for (int dt = 0; dt < 8; dt++) {
    int dcol = h * HD + dt * 16 + col;
    #pragma unroll
    for (int r = 0; r < 4; r++) {
      int rg = qrow + quad * 4 + r;
      ao[((size_t)(b * S_LEN) + rg) * DIM_ + dcol] = f2bf(o[dt][r] * linv[r]);
    }
  }
}

extern "C" void kernel_launch(void* const* d_in, const int* in_sizes, int n_in,
                              void* d_out, int out_size, void* d_ws, size_t ws_size,
                              hipStream_t stream) {
  const float* x  = (const float*)d_in[0];
  const float* fc = (const float*)d_in[1];
  const float* fs = (const float*)d_in[2];
  const float* wq = (const float*)d_in[3];
  const float* wk = (const float*)d_in[4];
  const float* wv = (const float*)d_in[5];
  const float* wo = (const float*)d_in[6];
  float* out = (float*)d_out;

  char* ws = (char*)d_ws;
  const size_t MB = 1024 * 1024;
  unsigned short* xb    = (unsigned short*)(ws + 0 * MB);    // 4096x2048 bf16 (16 MiB)
  unsigned short* wqkvT = (unsigned short*)(ws + 16 * MB);   // 4096x2048      (16 MiB)
  unsigned short* woT   = (unsigned short*)(ws + 32 * MB);   // 2048x2048      (8 MiB)
  unsigned short* qb    = (unsigned short*)(ws + 40 * MB);   // 4096x2048      (16 MiB)
  unsigned short* kb    = (unsigned short*)(ws + 56 * MB);   // 4096x1024      (8 MiB)
  unsigned short* vT    = (unsigned short*)(ws + 64 * MB);   // (b,kvh,d,s)    (8 MiB)
  unsigned short* ao    = (unsigned short*)(ws + 72 * MB);   // 4096x2048      (16 MiB)

  // prep: convert x + transpose-convert all weights (one dispatch)
  k_prep<<<dim3(20480), dim3(256), 0, stream>>>(x, xb, wq, wk, wv, wo, wqkvT, woT);
  // fused QKV projection + RoPE (+q pre-scale) + V transpose: 256x256, 1 block/CU, pipelined
  k_gemm256<3, 256><<<dim3(16, 16), dim3(512), 0, stream>>>(xb, wqkvT, (void*)qb, 4096, 2048, fc, fs, kb, vT);
  // attention: swapped-QK softmax + async staging, 2 blocks/CU
  k_attn<<<dim3(16, 32), dim3(512), 0, stream>>>(qb, kb, vT, ao);
  // output projection (f32 out): 128x256 tiles -> grid (8,32) = 1 block/CU, pipelined
  k_gemm256<1, 128><<<dim3(8, 32), dim3(512), 0, stream>>>(ao, woT, (void*)out, 2048, 2048, nullptr, nullptr, nullptr, nullptr);
}

// Round 6
// 331.260 us; speedup vs baseline: 1.1229x; 1.1229x over previous
//
#include <hip/hip_runtime.h>
#include <cstdint>
#include <cstddef>

#define S_LEN 2048
#define DIM_   2048
#define NH   16
#define NKV  8
#define HD   128

typedef __attribute__((ext_vector_type(8))) __bf16 bf16x8;
typedef __attribute__((ext_vector_type(4))) float  f32x4;

typedef const __attribute__((address_space(1))) void* gptr_t;
typedef __attribute__((address_space(3))) void*       sptr_t;

static __device__ __forceinline__ float bf2f(unsigned short u) {
  union { unsigned int i; float f; } v; v.i = ((unsigned int)u) << 16; return v.f;
}
static __device__ __forceinline__ unsigned short f2bf(float f) {
  union { float f; unsigned int i; } v; v.f = f;
  unsigned int u = v.i;
  unsigned int r = (u + 0x7FFFu + ((u >> 16) & 1u)) >> 16;
  return (unsigned short)r;
}

// scale(1/sqrt(128)) * log2(e) — folded into q so softmax uses exp2 directly
#define QSCALE 0.12751744f
// defer-max threshold (T13): 8 in ln-domain -> 8*log2(e) in exp2-domain
#define RESC_THR 11.542f

// ---------------- prep: x->bf16 convert + 4 weight transpose-converts ----------------
__global__ void k_prep(const float* __restrict__ x, unsigned short* __restrict__ xb,
                       const float* __restrict__ wq, const float* __restrict__ wk,
                       const float* __restrict__ wv, const float* __restrict__ wo,
                       unsigned short* __restrict__ wqkvT, unsigned short* __restrict__ woT) {
  int bid = blockIdx.x;
  if (bid < 8192) {
    int i = bid * 256 + threadIdx.x;
    float4 v = ((const float4*)x)[i];
    ushort4 o; o.x = f2bf(v.x); o.y = f2bf(v.y); o.z = f2bf(v.z); o.w = f2bf(v.w);
    ((ushort4*)xb)[i] = o;
    return;
  }
  bid -= 8192;
  const float* src; unsigned short* dst; int N, ntx;
  if (bid < 4096)      { src = wq; dst = wqkvT;                       N = 2048; ntx = 64; }
  else if (bid < 6144) { bid -= 4096; src = wk; dst = wqkvT + (size_t)2048 * 2048; N = 1024; ntx = 32; }
  else if (bid < 8192) { bid -= 6144; src = wv; dst = wqkvT + (size_t)3072 * 2048; N = 1024; ntx = 32; }
  else                 { bid -= 8192; src = wo; dst = woT;            N = 2048; ntx = 64; }
  const int K = 2048;
  __shared__ float tile[32][33];
  int lx = threadIdx.x & 31, ly = threadIdx.x >> 5; // 32 x 8
  int r0 = (bid / ntx) * 32, c0 = (bid % ntx) * 32;
  #pragma unroll
  for (int r = 0; r < 32; r += 8)
    tile[ly + r][lx] = src[(size_t)(r0 + ly + r) * N + c0 + lx];
  __syncthreads();
  #pragma unroll
  for (int r = 0; r < 32; r += 8)
    dst[(size_t)(c0 + ly + r) * K + r0 + lx] = f2bf(tile[lx][ly + r]);
}

// ------------- GEMM: C(MxN) = A(MxK) * BT(NxK)^T, bf16 in, fp32 acc -------------
// PROVEN 2-barrier template (rounds 2-4), generalized over <MODE, BM_, TPB>.
// BK=64, XOR-swizzled LDS via source permutation (bank-conflict 0 measured).
// Tile BM_ x 128.
//   BM_=256/TPB=512: 8 waves 4Mx2N, per-wave 64x64 (acc[4][4] - proven shape).
//     grid 512 blocks = 2/CU (VGPR-capped), L2 read traffic 1 GB (half of 128-sq).
//   BM_=128/TPB=256: 4 waves 2Mx2N (round-4 config).
//   BM_=64 /TPB=256: 4 waves 1Mx4N, per-wave 64x32 (round-4 MODE1 config, 4/CU).
// ROUND-3 LESSON: wall = NT x L when resident; concurrency and per-iter work set L.
// ROUND-5 LESSON: 256-sq/BK32/4-ring/counted-vmcnt at 1 block/CU REGRESSED
//   (123us, MfmaUtil 22.8): no intra-iteration interleave + no TLP fallback.
//   Do not retry deep pipelining without a faithful 8-phase port.
// MODE 1: store f32 natural C[m][n]
// MODE 3: fused QKV epilogue (q+RoPE*QSCALE | k+RoPE | v transposed).
template<int MODE, int BM_, int TPB>
__global__ __launch_bounds__(TPB, 2) void k_gemm_bt(
    const unsigned short* __restrict__ A, const unsigned short* __restrict__ BT,
    void* __restrict__ C, int N, int K,
    const float* __restrict__ fc, const float* __restrict__ fs,
    unsigned short* __restrict__ kb, unsigned short* __restrict__ vb) {
  constexpr int NI = (BM_ == 64) ? 2 : 4;          // B-frags per wave
  constexpr int AR = (BM_ * 64) / (TPB * 8);       // A staging rounds
  constexpr int BR = (128 * 64) / (TPB * 8);       // B staging rounds
  __shared__ __align__(16) unsigned short Asm[BM_ * 64];
  __shared__ __align__(16) unsigned short Bsm[128 * 64];
  const int t = threadIdx.x;
  const int lane = t & 63, w = t >> 6;
  const int wm = (BM_ == 64) ? 0 : (w >> 1) * 64;
  const int wn = (BM_ == 64) ? w * 32 : (w & 1) * 64;
  const int col = lane & 15, quad = lane >> 4;
  const int m0 = blockIdx.y * BM_, n0 = blockIdx.x * 128;

  f32x4 acc[4][NI];
  #pragma unroll
  for (int i = 0; i < 4; i++)
    #pragma unroll
    for (int j = 0; j < NI; j++) acc[i][j] = (f32x4){0.f, 0.f, 0.f, 0.f};

  for (int kk = 0; kk < K; kk += 64) {
    #pragma unroll
    for (int r = 0; r < AR; ++r) {   // A: BM_ rows x 64
      int c = t + r * TPB;
      int c0 = (t & ~63) + r * TPB;   // wave-uniform chunk base
      int row = c >> 3;
      int kcs = (c & 7) ^ (row & 7);  // source permutation = target swizzle
      const unsigned short* gA = A + (size_t)(m0 + row) * K + kk + kcs * 8;
      __builtin_amdgcn_global_load_lds((gptr_t)gA, (sptr_t)(&Asm[c0 * 8]), 16, 0, 0);
    }
    #pragma unroll
    for (int r = 0; r < BR; ++r) {   // B: 128 rows x 64
      int c = t + r * TPB;
      int c0 = (t & ~63) + r * TPB;
      int row = c >> 3;
      int kcs = (c & 7) ^ (row & 7);
      const unsigned short* gB = BT + (size_t)(n0 + row) * K + kk + kcs * 8;
      __builtin_amdgcn_global_load_lds((gptr_t)gB, (sptr_t)(&Bsm[c0 * 8]), 16, 0, 0);
    }
    __syncthreads();
    #pragma unroll
    for (int kc2 = 0; kc2 < 2; kc2++) {
      bf16x8 af[4], bf[NI];
      #pragma unroll
      for (int mi = 0; mi < 4; mi++) {
        int rowA = wm + mi * 16 + col;
        af[mi] = *(const bf16x8*)(&Asm[rowA * 64 + (((kc2 * 4 + quad) ^ (col & 7)) * 8)]);
      }
      #pragma unroll
      for (int ni = 0; ni < NI; ni++) {
        int rowB = wn + ni * 16 + col;
        bf[ni] = *(const bf16x8*)(&Bsm[rowB * 64 + (((kc2 * 4 + quad) ^ (col & 7)) * 8)]);
      }
      __builtin_amdgcn_s_setprio(1);
      #pragma unroll
      for (int mi = 0; mi < 4; mi++)
        #pragma unroll
        for (int ni = 0; ni < NI; ni++)
          acc[mi][ni] = __builtin_amdgcn_mfma_f32_16x16x32_bf16(af[mi], bf[ni], acc[mi][ni], 0, 0, 0);
      __builtin_amdgcn_s_setprio(0);
    }
    __syncthreads();
  }

  #pragma unroll
  for (int mi = 0; mi < 4; mi++) {
    int row_base = m0 + wm + mi * 16 + quad * 4;
    #pragma unroll
    for (int ni = 0; ni < NI; ni++) {
      int col_g = n0 + wn + ni * 16 + col;
      if (MODE == 1) {
        float* O = (float*)C;
        #pragma unroll
        for (int r = 0; r < 4; r++) O[(size_t)(row_base + r) * N + col_g] = acc[mi][ni][r];
      } else {  // MODE 3
        int region = col_g >> 10;  // 0,1: q ; 2: k ; 3: v
        if (region < 3) {
          int ri = (col_g & 127) >> 1;
          float sgn = (col_g & 1) ? 1.f : -1.f;
          unsigned short* qO = (unsigned short*)C;
          #pragma unroll
          for (int r = 0; r < 4; r++) {
            int row = row_base + r;
            int s = row & (S_LEN - 1);
            float cv = fc[s * 64 + ri], sv = fs[s * 64 + ri];
            float val = acc[mi][ni][r];
            float other = __shfl_xor(val, 1);
            float res = val * cv + sgn * other * sv;
            if (region < 2) qO[(size_t)row * 2048 + col_g] = f2bf(res * QSCALE);
            else            kb[(size_t)row * 1024 + (col_g - 2048)] = f2bf(res);
          }
        } else {
          int n_local = col_g - 3072;
          int b = row_base >> 11, s = row_base & (S_LEN - 1);
          int kvh = n_local >> 7, d = n_local & (HD - 1);
          ushort4 o4;
          o4.x = f2bf(acc[mi][ni][0]); o4.y = f2bf(acc[mi][ni][1]);
          o4.z = f2bf(acc[mi][ni][2]); o4.w = f2bf(acc[mi][ni][3]);
          *(ushort4*)(&vb[((size_t)((b * NKV + kvh) * HD + d)) * S_LEN + s]) = o4;
        }
      }
    }
  }
}

// ---------------- Flash attention, causal, GQA-shared K/V ----------------
// 512-thread blocks (8 waves = 2 heads x 4 waves), ONE q-tile per block,
// grid (16,32) = 2 blocks/CU. Swapped QK^T (lane owns a q-row: 15 local fmax
// + 2 shfl), async K/V staging (T14), defer-max (T13), setprio (T5).
// ROUND-1 LESSON: __launch_bounds__ 2nd arg acts as BLOCKS/CU here; (512,6)
// capped VGPR at 40 -> accumulator spill -> 225 MB scratch traffic.
#define KLD 136   // 128 + 8 (row-to-row bank offset 4 -> conflict-free frags)
#define VLD 72    // 64 + 8
__global__ __launch_bounds__(512, 2) void k_attn(
    const unsigned short* __restrict__ q, const unsigned short* __restrict__ k,
    const unsigned short* __restrict__ vT, unsigned short* __restrict__ ao) {
  __shared__ __align__(16) unsigned short Ksm[64 * KLD];       // 17408 B
  __shared__ __align__(16) unsigned short Vsm[128 * VLD];      // 18432 B
  __shared__ __align__(16) unsigned short Psm[8 * 16 * VLD];   // 18432 B
  const int t = threadIdx.x;
  const int lane = t & 63, w = t >> 6;        // 8 waves
  const int col = lane & 15, quad = lane >> 4;
  const int g = blockIdx.x;                   // b*NKV + kvh
  const int b = g >> 3, kvh = g & 7;
  const int h = kvh * 2 + (w >> 2);           // waves 0-3: head 2g, 4-7: head 2g+1
  const int yi = blockIdx.y;                  // 0..31
  const int my_qt = (yi < 16) ? yi : 47 - yi; // balanced long/short pairing
  const int qrow = my_qt * 64 + (w & 3) * 16; // this wave's 16 query rows
  unsigned short* Pw = &Psm[w * 16 * VLD];

  // staging addresses (per thread): 2 uint4 for K, 2 uint4 for V
  const int ki0 = t >> 4,        kdc = t & 15;         // K row / d-chunk
  const int ki1 = (t + 512) >> 4;
  const int vd0 = t >> 3,        vkc = t & 7;          // V d-row / key-chunk
  const int vd1 = (t + 512) >> 3;
  const unsigned short* kgp = k + (size_t)(b * S_LEN) * (NKV * HD) + kvh * HD + kdc * 8;
  const unsigned short* vgp = vT + ((size_t)(b * NKV + kvh) * HD) * S_LEN + vkc * 8;

  bf16x8 qf[4];
  const size_t qbase = ((size_t)(b * S_LEN) + qrow + col) * DIM_ + h * HD;
  #pragma unroll
  for (int kc = 0; kc < 4; kc++) qf[kc] = *(const bf16x8*)(q + qbase + kc * 32 + quad * 8);

  f32x4 o[8];
  #pragma unroll
  for (int i = 0; i < 8; i++) o[i] = (f32x4){0.f, 0.f, 0.f, 0.f};
  float m_i = -1e30f;   // running max for q-row (qrow + col)
  float l_i = 0.f;      // running denom for q-row (qrow + col)

  const int nkt = my_qt + 1;                  // wave-uniform causal range

  // prologue: stage tile 0
  {
    uint4 kr0 = *(const uint4*)(kgp + (size_t)ki0 * (NKV * HD));
    uint4 kr1 = *(const uint4*)(kgp + (size_t)ki1 * (NKV * HD));
    uint4 vr0 = *(const uint4*)(vgp + (size_t)vd0 * S_LEN);
    uint4 vr1 = *(const uint4*)(vgp + (size_t)vd1 * S_LEN);
    *(uint4*)(&Ksm[ki0 * KLD + kdc * 8]) = kr0;
    *(uint4*)(&Ksm[ki1 * KLD + kdc * 8]) = kr1;
    *(uint4*)(&Vsm[vd0 * VLD + vkc * 8]) = vr0;
    *(uint4*)(&Vsm[vd1 * VLD + vkc * 8]) = vr1;
  }
  __syncthreads();

  for (int kt = 0; kt < nkt; ++kt) {
    const bool more = (kt + 1 < nkt);         // block-uniform
    uint4 kr0, kr1, vr0, vr1;
    if (more) {                               // issue K(t+1) early: latency hides under QK+softmax
      kr0 = *(const uint4*)(kgp + (size_t)((kt + 1) * 64 + ki0) * (NKV * HD));
      kr1 = *(const uint4*)(kgp + (size_t)((kt + 1) * 64 + ki1) * (NKV * HD));
    }

    // ---- QK^T, swapped operands: p[nt][r] = P[key = kt*64+nt*16+quad*4+r][q = col]
    float p[4][4];
    __builtin_amdgcn_s_setprio(1);
    #pragma unroll
    for (int nt = 0; nt < 4; nt++) {
      f32x4 s_acc = (f32x4){0.f, 0.f, 0.f, 0.f};
      #pragma unroll
      for (int kc = 0; kc < 4; kc++) {
        bf16x8 kf = *(const bf16x8*)(&Ksm[(nt * 16 + col) * KLD + kc * 32 + quad * 8]);
        s_acc = __builtin_amdgcn_mfma_f32_16x16x32_bf16(kf, qf[kc], s_acc, 0, 0, 0);
      }
      #pragma unroll
      for (int r = 0; r < 4; r++) p[nt][r] = s_acc[r];
    }
    __builtin_amdgcn_s_setprio(0);

    if (kt == my_qt) {  // diagonal tile: causal mask (q = qrow+col, key per reg)
      const int qglob = qrow + col;
      #pragma unroll
      for (int nt = 0; nt < 4; nt++)
        #pragma unroll
        for (int r = 0; r < 4; r++)
          if (kt * 64 + nt * 16 + quad * 4 + r > qglob) p[nt][r] = -1e30f;
    }

    // ---- softmax for this lane's q-row: 15 local fmax + 2 shfl
    float mx = fmaxf(fmaxf(fmaxf(p[0][0], p[0][1]), fmaxf(p[0][2], p[0][3])),
                     fmaxf(fmaxf(p[1][0], p[1][1]), fmaxf(p[1][2], p[1][3])));
    mx = fmaxf(mx, fmaxf(fmaxf(fmaxf(p[2][0], p[2][1]), fmaxf(p[2][2], p[2][3])),
                         fmaxf(fmaxf(p[3][0], p[3][1]), fmaxf(p[3][2], p[3][3]))));
    mx = fmaxf(mx, __shfl_xor(mx, 16));
    mx = fmaxf(mx, __shfl_xor(mx, 32));
    if (__any(mx - m_i > RESC_THR)) {   // defer-max (T13): rare
      float mn = fmaxf(m_i, mx);
      float alpha = exp2f(m_i - mn);
      m_i = mn; l_i *= alpha;
      float ar[4];
      #pragma unroll
      for (int r = 0; r < 4; r++) ar[r] = __shfl(alpha, quad * 4 + r);
      #pragma unroll
      for (int dt = 0; dt < 8; dt++)
        #pragma unroll
        for (int r = 0; r < 4; r++) o[dt][r] *= ar[r];
    }
    float rs = 0.f;
    #pragma unroll
    for (int nt = 0; nt < 4; nt++)
      #pragma unroll
      for (int r = 0; r < 4; r++) {
        float e = exp2f(p[nt][r] - m_i);
        p[nt][r] = e;
        rs += e;
      }
    rs += __shfl_xor(rs, 16);
    rs += __shfl_xor(rs, 32);
    l_i += rs;

    // ---- P -> Pw (A-layout directly: Pw[q][key]), 4x packed b64 writes
    #pragma unroll
    for (int nt = 0; nt < 4; nt++) {
      unsigned int w0 = (unsigned int)f2bf(p[nt][0]) | ((unsigned int)f2bf(p[nt][1]) << 16);
      unsigned int w1 = (unsigned int)f2bf(p[nt][2]) | ((unsigned int)f2bf(p[nt][3]) << 16);
      uint2 pk; pk.x = w0; pk.y = w1;
      *(uint2*)(&Pw[col * VLD + nt * 16 + quad * 4]) = pk;
    }

    __syncthreads();   // B1: all waves done reading Ksm (and Pw writes drained)

    if (more) {        // K(t+1) -> LDS (overlaps PV), issue V(t+1) loads
      *(uint4*)(&Ksm[ki0 * KLD + kdc * 8]) = kr0;
      *(uint4*)(&Ksm[ki1 * KLD + kdc * 8]) = kr1;
      vr0 = *(const uint4*)(vgp + (size_t)vd0 * S_LEN + (kt + 1) * 64);
      vr1 = *(const uint4*)(vgp + (size_t)vd1 * S_LEN + (kt + 1) * 64);
    }

    bf16x8 pf[2];
    #pragma unroll
    for (int kc2 = 0; kc2 < 2; kc2++)
      pf[kc2] = *(const bf16x8*)(&Pw[col * VLD + kc2 * 32 + quad * 8]);

    // ---- O += P V
    __builtin_amdgcn_s_setprio(1);
    #pragma unroll
    for (int dt = 0; dt < 8; dt++) {
      #pragma unroll
      for (int kc2 = 0; kc2 < 2; kc2++) {
        bf16x8 vf = *(const bf16x8*)(&Vsm[(dt * 16 + col) * VLD + kc2 * 32 + quad * 8]);
        o[dt] = __builtin_amdgcn_mfma_f32_16x16x32_bf16(pf[kc2], vf, o[dt], 0, 0, 0);
      }
    }
    __builtin_amdgcn_s_setprio(0);

    __syncthreads();   // B2: all waves done reading Vsm; Ksm(t+1) visible

    if (more) {        // V(t+1) -> LDS (overlaps next QK)
      *(uint4*)(&Vsm[vd0 * VLD + vkc * 8]) = vr0;
      *(uint4*)(&Vsm[vd1 * VLD + vkc * 8]) = vr1;
    }
  }

  // epilogue: 1/l for this lane's four q-rows (col -> row permute, once)
  float linv[4];
  #pragma unroll
  for (int r = 0; r < 4; r++) linv[r] = 1.f / __shfl(l_i, quad * 4 + r);
  #pragma unroll
  for (int dt = 0; dt < 8; dt++) {
    int dcol = h * HD + dt * 16 + col;
    #pragma unroll
    for (int r = 0; r < 4; r++) {
      int rg = qrow + quad * 4 + r;
      ao[((size_t)(b * S_LEN) + rg) * DIM_ + dcol] = f2bf(o[dt][r] * linv[r]);
    }
  }
}

extern "C" void kernel_launch(void* const* d_in, const int* in_sizes, int n_in,
                              void* d_out, int out_size, void* d_ws, size_t ws_size,
                              hipStream_t stream) {
  const float* x  = (const float*)d_in[0];
  const float* fc = (const float*)d_in[1];
  const float* fs = (const float*)d_in[2];
  const float* wq = (const float*)d_in[3];
  const float* wk = (const float*)d_in[4];
  const float* wv = (const float*)d_in[5];
  const float* wo = (const float*)d_in[6];
  float* out = (float*)d_out;

  char* ws = (char*)d_ws;
  const size_t MB = 1024 * 1024;
  unsigned short* xb    = (unsigned short*)(ws + 0 * MB);    // 4096x2048 bf16 (16 MiB)
  unsigned short* wqkvT = (unsigned short*)(ws + 16 * MB);   // 4096x2048      (16 MiB)
  unsigned short* woT   = (unsigned short*)(ws + 32 * MB);   // 2048x2048      (8 MiB)
  unsigned short* qb    = (unsigned short*)(ws + 40 * MB);   // 4096x2048      (16 MiB)
  unsigned short* kb    = (unsigned short*)(ws + 56 * MB);   // 4096x1024      (8 MiB)
  unsigned short* vT    = (unsigned short*)(ws + 64 * MB);   // (b,kvh,d,s)    (8 MiB)
  unsigned short* ao    = (unsigned short*)(ws + 72 * MB);   // 4096x2048      (16 MiB)

  // prep: convert x + transpose-convert all weights (one dispatch)
  k_prep<<<dim3(20480), dim3(256), 0, stream>>>(x, xb, wq, wk, wv, wo, wqkvT, woT);
  // fused QKV projection + RoPE (+q pre-scale) + V transpose:
  // 256x128 tile, 8 waves, grid (32,16) = 512 blocks = 2/CU, halved L2 traffic
  k_gemm_bt<3, 256, 512><<<dim3(32, 16), dim3(512), 0, stream>>>(xb, wqkvT, (void*)qb, 4096, 2048, fc, fs, kb, vT);
  // attention: swapped-QK softmax + async staging, 2 blocks/CU
  k_attn<<<dim3(16, 32), dim3(512), 0, stream>>>(qb, kb, vT, ao);
  // output projection (f32 out): 64x128 tiles -> grid (16,64) = 4 blocks/CU (round-4 proven)
  k_gemm_bt<1, 64, 256><<<dim3(16, 64), dim3(256), 0, stream>>>(ao, woT, (void*)out, 2048, 2048, nullptr, nullptr, nullptr, nullptr);
}

// Round 7
// 318.420 us; speedup vs baseline: 1.1682x; 1.0403x over previous
//
#include <hip/hip_runtime.h>
#include <cstdint>
#include <cstddef>

#define S_LEN 2048
#define DIM_   2048
#define NH   16
#define NKV  8
#define HD   128

typedef __attribute__((ext_vector_type(8))) __bf16 bf16x8;
typedef __attribute__((ext_vector_type(4))) float  f32x4;

typedef const __attribute__((address_space(1))) void* gptr_t;
typedef __attribute__((address_space(3))) void*       sptr_t;

static __device__ __forceinline__ float bf2f(unsigned short u) {
  union { unsigned int i; float f; } v; v.i = ((unsigned int)u) << 16; return v.f;
}
static __device__ __forceinline__ unsigned short f2bf(float f) {
  union { float f; unsigned int i; } v; v.f = f;
  unsigned int u = v.i;
  unsigned int r = (u + 0x7FFFu + ((u >> 16) & 1u)) >> 16;
  return (unsigned short)r;
}

// scale(1/sqrt(128)) * log2(e) — folded into q so softmax uses exp2 directly
#define QSCALE 0.12751744f
// defer-max threshold (T13): 8 in ln-domain -> 8*log2(e) in exp2-domain
#define RESC_THR 11.542f

// ---------------- prep: x->bf16 convert + 4 weight transpose-converts ----------------
// ROUND-7: transpose path re-done as 64x64 tiles, float4 loads + packed ushort4
// stores (was 32x32 scalar loads / 2-byte scalar stores = Common-mistake #2).
// Blocks: 8192 convert + 3072 transpose.
__global__ void k_prep(const float* __restrict__ x, unsigned short* __restrict__ xb,
                       const float* __restrict__ wq, const float* __restrict__ wk,
                       const float* __restrict__ wv, const float* __restrict__ wo,
                       unsigned short* __restrict__ wqkvT, unsigned short* __restrict__ woT) {
  int bid = blockIdx.x;
  if (bid < 8192) {
    int i = bid * 256 + threadIdx.x;
    float4 v = ((const float4*)x)[i];
    ushort4 o; o.x = f2bf(v.x); o.y = f2bf(v.y); o.z = f2bf(v.z); o.w = f2bf(v.w);
    ((ushort4*)xb)[i] = o;
    return;
  }
  bid -= 8192;
  const float* src; unsigned short* dst; int N, ntx;
  if (bid < 1024)      { src = wq; dst = wqkvT;                       N = 2048; ntx = 32; }
  else if (bid < 1536) { bid -= 1024; src = wk; dst = wqkvT + (size_t)2048 * 2048; N = 1024; ntx = 16; }
  else if (bid < 2048) { bid -= 1536; src = wv; dst = wqkvT + (size_t)3072 * 2048; N = 1024; ntx = 16; }
  else                 { bid -= 2048; src = wo; dst = woT;            N = 2048; ntx = 32; }
  const int K = 2048;
  __shared__ float tile[64][65];
  int lx = threadIdx.x & 15, ly = threadIdx.x >> 4;  // 16 x 16
  int r0 = (bid / ntx) * 64, c0 = (bid % ntx) * 64;
  #pragma unroll
  for (int i = 0; i < 4; i++) {
    int row = ly + 16 * i;
    float4 v = *(const float4*)(&src[(size_t)(r0 + row) * N + c0 + lx * 4]);
    tile[row][lx * 4 + 0] = v.x; tile[row][lx * 4 + 1] = v.y;
    tile[row][lx * 4 + 2] = v.z; tile[row][lx * 4 + 3] = v.w;
  }
  __syncthreads();
  #pragma unroll
  for (int i = 0; i < 4; i++) {
    int nrow = ly + 16 * i;
    ushort4 o;
    o.x = f2bf(tile[lx * 4 + 0][nrow]); o.y = f2bf(tile[lx * 4 + 1][nrow]);
    o.z = f2bf(tile[lx * 4 + 2][nrow]); o.w = f2bf(tile[lx * 4 + 3][nrow]);
    *(ushort4*)(&dst[(size_t)(c0 + nrow) * K + r0 + lx * 4]) = o;
  }
}

// ------------- GEMM: C(MxN) = A(MxK) * BT(NxK)^T, bf16 in, fp32 acc -------------
// PROVEN 2-barrier template, generalized over <MODE, BM_, TPB>.
// BK=64, XOR-swizzled LDS via source permutation (bank-conflict 0 measured).
// TILE-SPACE MEASURED (MODE3, M4096 N4096 K2048):
//   128sq @4 blocks/CU = 86.5us (794 TF, MfmaUtil 35)  <- BEST, use this
//   256x128 @2/CU      = 100us  (MfmaUtil 28)
//   256sq @1/CU piped  = 123us  (MfmaUtil 23)
// => in this structure TLP (blocks/CU) dominates tile density (m99/m100:
//    implicit wave-overlap hides staging; do not trade residency away).
// ROUND-5 LESSON: coarse counted-vmcnt ring w/o per-phase interleave regresses.
// MODE 1: store f32 natural C[m][n]
// MODE 3: fused QKV epilogue (q+RoPE*QSCALE | k+RoPE | v transposed).
template<int MODE, int BM_, int TPB>
__global__ __launch_bounds__(TPB, 2) void k_gemm_bt(
    const unsigned short* __restrict__ A, const unsigned short* __restrict__ BT,
    void* __restrict__ C, int N, int K,
    const float* __restrict__ fc, const float* __restrict__ fs,
    unsigned short* __restrict__ kb, unsigned short* __restrict__ vb) {
  constexpr int NI = (BM_ == 64) ? 2 : 4;          // B-frags per wave
  constexpr int AR = (BM_ * 64) / (TPB * 8);       // A staging rounds
  constexpr int BR = (128 * 64) / (TPB * 8);       // B staging rounds
  __shared__ __align__(16) unsigned short Asm[BM_ * 64];
  __shared__ __align__(16) unsigned short Bsm[128 * 64];
  const int t = threadIdx.x;
  const int lane = t & 63, w = t >> 6;
  const int wm = (BM_ == 64) ? 0 : (w >> 1) * 64;
  const int wn = (BM_ == 64) ? w * 32 : (w & 1) * 64;
  const int col = lane & 15, quad = lane >> 4;
  const int m0 = blockIdx.y * BM_, n0 = blockIdx.x * 128;

  f32x4 acc[4][NI];
  #pragma unroll
  for (int i = 0; i < 4; i++)
    #pragma unroll
    for (int j = 0; j < NI; j++) acc[i][j] = (f32x4){0.f, 0.f, 0.f, 0.f};

  for (int kk = 0; kk < K; kk += 64) {
    #pragma unroll
    for (int r = 0; r < AR; ++r) {   // A: BM_ rows x 64
      int c = t + r * TPB;
      int c0 = (t & ~63) + r * TPB;   // wave-uniform chunk base
      int row = c >> 3;
      int kcs = (c & 7) ^ (row & 7);  // source permutation = target swizzle
      const unsigned short* gA = A + (size_t)(m0 + row) * K + kk + kcs * 8;
      __builtin_amdgcn_global_load_lds((gptr_t)gA, (sptr_t)(&Asm[c0 * 8]), 16, 0, 0);
    }
    #pragma unroll
    for (int r = 0; r < BR; ++r) {   // B: 128 rows x 64
      int c = t + r * TPB;
      int c0 = (t & ~63) + r * TPB;
      int row = c >> 3;
      int kcs = (c & 7) ^ (row & 7);
      const unsigned short* gB = BT + (size_t)(n0 + row) * K + kk + kcs * 8;
      __builtin_amdgcn_global_load_lds((gptr_t)gB, (sptr_t)(&Bsm[c0 * 8]), 16, 0, 0);
    }
    __syncthreads();
    #pragma unroll
    for (int kc2 = 0; kc2 < 2; kc2++) {
      bf16x8 af[4], bf[NI];
      #pragma unroll
      for (int mi = 0; mi < 4; mi++) {
        int rowA = wm + mi * 16 + col;
        af[mi] = *(const bf16x8*)(&Asm[rowA * 64 + (((kc2 * 4 + quad) ^ (col & 7)) * 8)]);
      }
      #pragma unroll
      for (int ni = 0; ni < NI; ni++) {
        int rowB = wn + ni * 16 + col;
        bf[ni] = *(const bf16x8*)(&Bsm[rowB * 64 + (((kc2 * 4 + quad) ^ (col & 7)) * 8)]);
      }
      #pragma unroll
      for (int mi = 0; mi < 4; mi++)
        #pragma unroll
        for (int ni = 0; ni < NI; ni++)
          acc[mi][ni] = __builtin_amdgcn_mfma_f32_16x16x32_bf16(af[mi], bf[ni], acc[mi][ni], 0, 0, 0);
    }
    __syncthreads();
  }

  #pragma unroll
  for (int mi = 0; mi < 4; mi++) {
    int row_base = m0 + wm + mi * 16 + quad * 4;
    #pragma unroll
    for (int ni = 0; ni < NI; ni++) {
      int col_g = n0 + wn + ni * 16 + col;
      if (MODE == 1) {
        float* O = (float*)C;
        #pragma unroll
        for (int r = 0; r < 4; r++) O[(size_t)(row_base + r) * N + col_g] = acc[mi][ni][r];
      } else {  // MODE 3
        int region = col_g >> 10;  // 0,1: q ; 2: k ; 3: v
        if (region < 3) {
          int ri = (col_g & 127) >> 1;
          float sgn = (col_g & 1) ? 1.f : -1.f;
          unsigned short* qO = (unsigned short*)C;
          #pragma unroll
          for (int r = 0; r < 4; r++) {
            int row = row_base + r;
            int s = row & (S_LEN - 1);
            float cv = fc[s * 64 + ri], sv = fs[s * 64 + ri];
            float val = acc[mi][ni][r];
            float other = __shfl_xor(val, 1);
            float res = val * cv + sgn * other * sv;
            if (region < 2) qO[(size_t)row * 2048 + col_g] = f2bf(res * QSCALE);
            else            kb[(size_t)row * 1024 + (col_g - 2048)] = f2bf(res);
          }
        } else {
          int n_local = col_g - 3072;
          int b = row_base >> 11, s = row_base & (S_LEN - 1);
          int kvh = n_local >> 7, d = n_local & (HD - 1);
          ushort4 o4;
          o4.x = f2bf(acc[mi][ni][0]); o4.y = f2bf(acc[mi][ni][1]);
          o4.z = f2bf(acc[mi][ni][2]); o4.w = f2bf(acc[mi][ni][3]);
          *(ushort4*)(&vb[((size_t)((b * NKV + kvh) * HD + d)) * S_LEN + s]) = o4;
        }
      }
    }
  }
}

// ---------------- Flash attention, causal, GQA-shared K/V ----------------
// 512-thread blocks (8 waves = 2 heads x 4 waves), ONE q-tile per block,
// grid (16,32) = 2 blocks/CU. Swapped QK^T (lane owns a q-row: 15 local fmax
// + 2 shfl), async K/V staging (T14), defer-max (T13), setprio (T5).
// ROUND-1 LESSON: __launch_bounds__ 2nd arg acts as BLOCKS/CU here; (512,6)
// capped VGPR at 40 -> accumulator spill -> 225 MB scratch traffic.
#define KLD 136   // 128 + 8 (row-to-row bank offset 4 -> conflict-free frags)
#define VLD 72    // 64 + 8
__global__ __launch_bounds__(512, 2) void k_attn(
    const unsigned short* __restrict__ q, const unsigned short* __restrict__ k,
    const unsigned short* __restrict__ vT, unsigned short* __restrict__ ao) {
  __shared__ __align__(16) unsigned short Ksm[64 * KLD];       // 17408 B
  __shared__ __align__(16) unsigned short Vsm[128 * VLD];      // 18432 B
  __shared__ __align__(16) unsigned short Psm[8 * 16 * VLD];   // 18432 B
  const int t = threadIdx.x;
  const int lane = t & 63, w = t >> 6;        // 8 waves
  const int col = lane & 15, quad = lane >> 4;
  const int g = blockIdx.x;                   // b*NKV + kvh
  const int b = g >> 3, kvh = g & 7;
  const int h = kvh * 2 + (w >> 2);           // waves 0-3: head 2g, 4-7: head 2g+1
  const int yi = blockIdx.y;                  // 0..31
  const int my_qt = (yi < 16) ? yi : 47 - yi; // balanced long/short pairing
  const int qrow = my_qt * 64 + (w & 3) * 16; // this wave's 16 query rows
  unsigned short* Pw = &Psm[w * 16 * VLD];

  // staging addresses (per thread): 2 uint4 for K, 2 uint4 for V
  const int ki0 = t >> 4,        kdc = t & 15;         // K row / d-chunk
  const int ki1 = (t + 512) >> 4;
  const int vd0 = t >> 3,        vkc = t & 7;          // V d-row / key-chunk
  const int vd1 = (t + 512) >> 3;
  const unsigned short* kgp = k + (size_t)(b * S_LEN) * (NKV * HD) + kvh * HD + kdc * 8;
  const unsigned short* vgp = vT + ((size_t)(b * NKV + kvh) * HD) * S_LEN + vkc * 8;

  bf16x8 qf[4];
  const size_t qbase = ((size_t)(b * S_LEN) + qrow + col) * DIM_ + h * HD;
  #pragma unroll
  for (int kc = 0; kc < 4; kc++) qf[kc] = *(const bf16x8*)(q + qbase + kc * 32 + quad * 8);

  f32x4 o[8];
  #pragma unroll
  for (int i = 0; i < 8; i++) o[i] = (f32x4){0.f, 0.f, 0.f, 0.f};
  float m_i = -1e30f;   // running max for q-row (qrow + col)
  float l_i = 0.f;      // running denom for q-row (qrow + col)

  const int nkt = my_qt + 1;                  // wave-uniform causal range

  // prologue: stage tile 0
  {
    uint4 kr0 = *(const uint4*)(kgp + (size_t)ki0 * (NKV * HD));
    uint4 kr1 = *(const uint4*)(kgp + (size_t)ki1 * (NKV * HD));
    uint4 vr0 = *(const uint4*)(vgp + (size_t)vd0 * S_LEN);
    uint4 vr1 = *(const uint4*)(vgp + (size_t)vd1 * S_LEN);
    *(uint4*)(&Ksm[ki0 * KLD + kdc * 8]) = kr0;
    *(uint4*)(&Ksm[ki1 * KLD + kdc * 8]) = kr1;
    *(uint4*)(&Vsm[vd0 * VLD + vkc * 8]) = vr0;
    *(uint4*)(&Vsm[vd1 * VLD + vkc * 8]) = vr1;
  }
  __syncthreads();

  for (int kt = 0; kt < nkt; ++kt) {
    const bool more = (kt + 1 < nkt);         // block-uniform
    uint4 kr0, kr1, vr0, vr1;
    if (more) {                               // issue K(t+1) early: latency hides under QK+softmax
      kr0 = *(const uint4*)(kgp + (size_t)((kt + 1) * 64 + ki0) * (NKV * HD));
      kr1 = *(const uint4*)(kgp + (size_t)((kt + 1) * 64 + ki1) * (NKV * HD));
    }

    // ---- QK^T, swapped operands: p[nt][r] = P[key = kt*64+nt*16+quad*4+r][q = col]
    float p[4][4];
    __builtin_amdgcn_s_setprio(1);
    #pragma unroll
    for (int nt = 0; nt < 4; nt++) {
      f32x4 s_acc = (f32x4){0.f, 0.f, 0.f, 0.f};
      #pragma unroll
      for (int kc = 0; kc < 4; kc++) {
        bf16x8 kf = *(const bf16x8*)(&Ksm[(nt * 16 + col) * KLD + kc * 32 + quad * 8]);
        s_acc = __builtin_amdgcn_mfma_f32_16x16x32_bf16(kf, qf[kc], s_acc, 0, 0, 0);
      }
      #pragma unroll
      for (int r = 0; r < 4; r++) p[nt][r] = s_acc[r];
    }
    __builtin_amdgcn_s_setprio(0);

    if (kt == my_qt) {  // diagonal tile: causal mask (q = qrow+col, key per reg)
      const int qglob = qrow + col;
      #pragma unroll
      for (int nt = 0; nt < 4; nt++)
        #pragma unroll
        for (int r = 0; r < 4; r++)
          if (kt * 64 + nt * 16 + quad * 4 + r > qglob) p[nt][r] = -1e30f;
    }

    // ---- softmax for this lane's q-row: 15 local fmax + 2 shfl
    float mx = fmaxf(fmaxf(fmaxf(p[0][0], p[0][1]), fmaxf(p[0][2], p[0][3])),
                     fmaxf(fmaxf(p[1][0], p[1][1]), fmaxf(p[1][2], p[1][3])));
    mx = fmaxf(mx, fmaxf(fmaxf(fmaxf(p[2][0], p[2][1]), fmaxf(p[2][2], p[2][3])),
                         fmaxf(fmaxf(p[3][0], p[3][1]), fmaxf(p[3][2], p[3][3]))));
    mx = fmaxf(mx, __shfl_xor(mx, 16));
    mx = fmaxf(mx, __shfl_xor(mx, 32));
    if (__any(mx - m_i > RESC_THR)) {   // defer-max (T13): rare
      float mn = fmaxf(m_i, mx);
      float alpha = exp2f(m_i - mn);
      m_i = mn; l_i *= alpha;
      float ar[4];
      #pragma unroll
      for (int r = 0; r < 4; r++) ar[r] = __shfl(alpha, quad * 4 + r);
      #pragma unroll
      for (int dt = 0; dt < 8; dt++)
        #pragma unroll
        for (int r = 0; r < 4; r++) o[dt][r] *= ar[r];
    }
    float rs = 0.f;
    #pragma unroll
    for (int nt = 0; nt < 4; nt++)
      #pragma unroll
      for (int r = 0; r < 4; r++) {
        float e = exp2f(p[nt][r] - m_i);
        p[nt][r] = e;
        rs += e;
      }
    rs += __shfl_xor(rs, 16);
    rs += __shfl_xor(rs, 32);
    l_i += rs;

    // ---- P -> Pw (A-layout directly: Pw[q][key]), 4x packed b64 writes
    #pragma unroll
    for (int nt = 0; nt < 4; nt++) {
      unsigned int w0 = (unsigned int)f2bf(p[nt][0]) | ((unsigned int)f2bf(p[nt][1]) << 16);
      unsigned int w1 = (unsigned int)f2bf(p[nt][2]) | ((unsigned int)f2bf(p[nt][3]) << 16);
      uint2 pk; pk.x = w0; pk.y = w1;
      *(uint2*)(&Pw[col * VLD + nt * 16 + quad * 4]) = pk;
    }

    __syncthreads();   // B1: all waves done reading Ksm (and Pw writes drained)

    if (more) {        // K(t+1) -> LDS (overlaps PV), issue V(t+1) loads
      *(uint4*)(&Ksm[ki0 * KLD + kdc * 8]) = kr0;
      *(uint4*)(&Ksm[ki1 * KLD + kdc * 8]) = kr1;
      vr0 = *(const uint4*)(vgp + (size_t)vd0 * S_LEN + (kt + 1) * 64);
      vr1 = *(const uint4*)(vgp + (size_t)vd1 * S_LEN + (kt + 1) * 64);
    }

    bf16x8 pf[2];
    #pragma unroll
    for (int kc2 = 0; kc2 < 2; kc2++)
      pf[kc2] = *(const bf16x8*)(&Pw[col * VLD + kc2 * 32 + quad * 8]);

    // ---- O += P V
    __builtin_amdgcn_s_setprio(1);
    #pragma unroll
    for (int dt = 0; dt < 8; dt++) {
      #pragma unroll
      for (int kc2 = 0; kc2 < 2; kc2++) {
        bf16x8 vf = *(const bf16x8*)(&Vsm[(dt * 16 + col) * VLD + kc2 * 32 + quad * 8]);
        o[dt] = __builtin_amdgcn_mfma_f32_16x16x32_bf16(pf[kc2], vf, o[dt], 0, 0, 0);
      }
    }
    __builtin_amdgcn_s_setprio(0);

    __syncthreads();   // B2: all waves done reading Vsm; Ksm(t+1) visible

    if (more) {        // V(t+1) -> LDS (overlaps next QK)
      *(uint4*)(&Vsm[vd0 * VLD + vkc * 8]) = vr0;
      *(uint4*)(&Vsm[vd1 * VLD + vkc * 8]) = vr1;
    }
  }

  // epilogue: 1/l for this lane's four q-rows (col -> row permute, once)
  float linv[4];
  #pragma unroll
  for (int r = 0; r < 4; r++) linv[r] = 1.f / __shfl(l_i, quad * 4 + r);
  #pragma unroll
  for (int dt = 0; dt < 8; dt++) {
    int dcol = h * HD + dt * 16 + col;
    #pragma unroll
    for (int r = 0; r < 4; r++) {
      int rg = qrow + quad * 4 + r;
      ao[((size_t)(b * S_LEN) + rg) * DIM_ + dcol] = f2bf(o[dt][r] * linv[r]);
    }
  }
}

extern "C" void kernel_launch(void* const* d_in, const int* in_sizes, int n_in,
                              void* d_out, int out_size, void* d_ws, size_t ws_size,
                              hipStream_t stream) {
  const float* x  = (const float*)d_in[0];
  const float* fc = (const float*)d_in[1];
  const float* fs = (const float*)d_in[2];
  const float* wq = (const float*)d_in[3];
  const float* wk = (const float*)d_in[4];
  const float* wv = (const float*)d_in[5];
  const float* wo = (const float*)d_in[6];
  float* out = (float*)d_out;

  char* ws = (char*)d_ws;
  const size_t MB = 1024 * 1024;
  unsigned short* xb    = (unsigned short*)(ws + 0 * MB);    // 4096x2048 bf16 (16 MiB)
  unsigned short* wqkvT = (unsigned short*)(ws + 16 * MB);   // 4096x2048      (16 MiB)
  unsigned short* woT   = (unsigned short*)(ws + 32 * MB);   // 2048x2048      (8 MiB)
  unsigned short* qb    = (unsigned short*)(ws + 40 * MB);   // 4096x2048      (16 MiB)
  unsigned short* kb    = (unsigned short*)(ws + 56 * MB);   // 4096x1024      (8 MiB)
  unsigned short* vT    = (unsigned short*)(ws + 64 * MB);   // (b,kvh,d,s)    (8 MiB)
  unsigned short* ao    = (unsigned short*)(ws + 72 * MB);   // 4096x2048      (16 MiB)

  // prep: convert x + transpose-convert all weights (vectorized 64x64 transpose)
  k_prep<<<dim3(11264), dim3(256), 0, stream>>>(x, xb, wq, wk, wv, wo, wqkvT, woT);
  // fused QKV projection + RoPE (+q pre-scale) + V transpose: 128sq, 4 blocks/CU (proven best)
  k_gemm_bt<3, 128, 256><<<dim3(32, 32), dim3(256), 0, stream>>>(xb, wqkvT, (void*)qb, 4096, 2048, fc, fs, kb, vT);
  // attention: swapped-QK softmax + async staging, 2 blocks/CU
  k_attn<<<dim3(16, 32), dim3(512), 0, stream>>>(qb, kb, vT, ao);
  // output projection (f32 out): 64x128 tiles -> grid (16,64) = 4 blocks/CU (round-4 proven)
  k_gemm_bt<1, 64, 256><<<dim3(16, 64), dim3(256), 0, stream>>>(ao, woT, (void*)out, 2048, 2048, nullptr, nullptr, nullptr, nullptr);
}